// Round 13
// baseline (251.648 us; speedup 1.0000x reference)
//
#include <hip/hip_runtime.h>

#define N_NODES 50000
#define N_EDGES 800000
#define D 128
#define N_LAYERS 3
#define NBUCK ((N_NODES + 255) / 256)       // 196 coarse buckets (256 nodes each)

typedef __attribute__((ext_vector_type(8))) short bfrag;
typedef __attribute__((ext_vector_type(4))) float f32x4;
typedef __attribute__((ext_vector_type(8))) unsigned short u16x8;

__device__ __forceinline__ unsigned short f2bf_rn(float f) {
    union { float f; unsigned u; } a; a.f = f;
    unsigned r = a.u + 0x7fffu + ((a.u >> 16) & 1u);
    return (unsigned short)(r >> 16);
}
__device__ __forceinline__ float bf2f(unsigned short h) {
    union { unsigned u; float f; } a; a.u = ((unsigned)h) << 16;
    return a.f;
}
__device__ __forceinline__ unsigned short f2h(float f) {
    union { unsigned short s[1]; _Float16 h; } a; a.h = (_Float16)f; return a.s[0];
}
__device__ __forceinline__ float h2f(unsigned short u) {
    union { unsigned short s[1]; _Float16 h; } a; a.s[0] = u; return (float)a.h;
}

#define GLOAD16(g, l) __builtin_amdgcn_global_load_lds( \
    (const __attribute__((address_space(1))) void*)(g), \
    (__attribute__((address_space(3))) void*)(l), 16, 0, 0)

// ---------------- detect dtype + zero coarse histogram & cursors ----------------
__global__ void detect_dtype_kernel(const unsigned int* __restrict__ edge, int* __restrict__ flag,
                                    int* __restrict__ gcoarse, int* __restrict__ cursor1) {
    __shared__ int any_nz;
    if (threadIdx.x == 0) any_nz = 0;
    __syncthreads();
    int nz = 0;
    for (int i = threadIdx.x; i < 2048; i += blockDim.x) {
        if (edge[2 * i + 1] != 0u) nz = 1;
    }
    if (nz) atomicOr(&any_nz, 1);
    for (int i = threadIdx.x; i < NBUCK; i += blockDim.x) { gcoarse[i] = 0; cursor1[i] = 0; }
    __syncthreads();
    if (threadIdx.x == 0) *flag = any_nz ? 0 : 1;   // 1 => int64 layout
}

// ---------------- coarse histogram (196 bins) straight off edge buffer ----------------
__global__ __launch_bounds__(256) void hist_coarse_kernel(const int* __restrict__ edge,
                                                          const int* __restrict__ flag,
                                                          int* __restrict__ gcoarse) {
    __shared__ int h[NBUCK];
    const int t = threadIdx.x;
    for (int i = t; i < NBUCK; i += 256) h[i] = 0;
    __syncthreads();
    const int flagv = *flag;
    const int base = blockIdx.x * 1024;
#pragma unroll
    for (int j = 0; j < 4; ++j) {
        int i = base + j * 256 + t;
        if (i < N_EDGES) {
            int d = flagv ? edge[2 * ((size_t)N_EDGES + i)] : edge[N_EDGES + i];
            atomicAdd(&h[d >> 8], 1);
        }
    }
    __syncthreads();
    for (int i = t; i < NBUCK; i += 256)
        if (h[i]) atomicAdd(&gcoarse[i], h[i]);
}

// ---------------- pass 1: coarse bucket scatter; bucket bases computed locally -------
__global__ __launch_bounds__(256) void pass1_kernel(const int* __restrict__ edge,
                                                    const int* __restrict__ flag,
                                                    const int* __restrict__ gcoarse,
                                                    int* __restrict__ cursor1,
                                                    int* __restrict__ packed) {
    __shared__ int hist[NBUCK];
    __shared__ int lbase[256];
    __shared__ int base[NBUCK];
    const int t = threadIdx.x;
    const int flagv = *flag;
    const int blockBeg = blockIdx.x * 4096;
    for (int i = t; i < NBUCK; i += 256) hist[i] = 0;
    // local exclusive scan of gcoarse -> lbase
    {
        int v = (t < NBUCK) ? gcoarse[t] : 0;
        lbase[t] = v;
        __syncthreads();
        for (int off = 1; off < 256; off <<= 1) {
            int u = (t >= off) ? lbase[t - off] : 0;
            __syncthreads();
            lbase[t] += u;
            __syncthreads();
        }
        lbase[t] -= v;   // exclusive
    }
    int es[16], ed[16];
#pragma unroll
    for (int j = 0; j < 16; ++j) {
        int e = blockBeg + j * 256 + t;   // coalesced
        if (e < N_EDGES) {
            if (flagv) { es[j] = edge[2 * (size_t)e]; ed[j] = edge[2 * ((size_t)N_EDGES + e)]; }
            else       { es[j] = edge[e];             ed[j] = edge[N_EDGES + e]; }
        } else ed[j] = -1;
    }
#pragma unroll
    for (int j = 0; j < 16; ++j)
        if (ed[j] >= 0) atomicAdd(&hist[ed[j] >> 8], 1);
    __syncthreads();
    for (int i = t; i < NBUCK; i += 256) {
        base[i] = lbase[i] + atomicAdd(&cursor1[i], hist[i]);
        hist[i] = 0;                       // reuse as within-block cursor
    }
    __syncthreads();
#pragma unroll
    for (int j = 0; j < 16; ++j) {
        if (ed[j] >= 0) {
            int b = ed[j] >> 8;
            int pos = base[b] + atomicAdd(&hist[b], 1);
            packed[pos] = ((ed[j] & 255) << 18) | es[j];
        }
    }
}

// ---------------- build CSR: local bucket bases + per-bucket count/scan/scatter ------
__global__ __launch_bounds__(256) void build_csr_kernel(const int* __restrict__ gcoarse,
                                                        const int* __restrict__ packed,
                                                        int* __restrict__ offsets,
                                                        float* __restrict__ inv_deg,
                                                        int* __restrict__ csr) {
    __shared__ int cnt[256];
    __shared__ int s[256];
    __shared__ int lbase[256];
    const int t = threadIdx.x;
    const int b = blockIdx.x;
    // local exclusive scan of gcoarse for this block's base + end
    {
        int v = (t < NBUCK) ? gcoarse[t] : 0;
        lbase[t] = v;
        __syncthreads();
        for (int off = 1; off < 256; off <<= 1) {
            int u = (t >= off) ? lbase[t - off] : 0;
            __syncthreads();
            lbase[t] += u;
            __syncthreads();
        }
    }
    const int base = (b == 0) ? 0 : lbase[b - 1];
    const int endb = lbase[b];
    cnt[t] = 0;
    __syncthreads();
    for (int e = base + t; e < endb; e += 256)
        atomicAdd(&cnt[((unsigned)packed[e]) >> 18], 1);
    __syncthreads();
    int v = cnt[t];
    s[t] = v;
    __syncthreads();
    for (int off = 1; off < 256; off <<= 1) {
        int u = (t >= off) ? s[t - off] : 0;
        __syncthreads();
        s[t] += u;
        __syncthreads();
    }
    int excl = base + s[t] - v;
    int node = b * 256 + t;
    if (node < N_NODES) {
        offsets[node] = excl;
        inv_deg[node] = 1.0f / (float)max(v, 1);
    }
    if (b == NBUCK - 1 && t == 0) offsets[N_NODES] = N_EDGES;
    cnt[t] = excl;                        // reuse as per-node cursor
    __syncthreads();
    for (int e = base + t; e < endb; e += 256) {
        int p = packed[e];
        int pos = atomicAdd(&cnt[((unsigned)p) >> 18], 1);
        csr[pos] = p & 0x3FFFF;
    }
}

// ---------------- weight split: Wt[l][j][k] (k contiguous), hi/lo bf16 ----------------
__global__ void prep_w_kernel(const float* __restrict__ Wl, const float* __restrict__ Wr,
                              unsigned short* __restrict__ WH, unsigned short* __restrict__ WL) {
    int idx = blockIdx.x * blockDim.x + threadIdx.x;
    if (idx >= N_LAYERS * 128 * 256) return;
    int k = idx & 255;
    int j = (idx >> 8) & 127;
    int l = idx >> 15;
    float v = (k < 128) ? Wl[((size_t)l * 128 + j) * 128 + k]
                        : Wr[((size_t)l * 128 + j) * 128 + (k - 128)];
    unsigned short hi = f2bf_rn(v);
    WH[idx] = hi;
    WL[idx] = f2bf_rn(v - bf2f(hi));
}

// ---------------- x -> fp16 ----------------
__global__ void split_x_kernel(const float* __restrict__ x, unsigned short* __restrict__ H16) {
    int t = blockIdx.x * 256 + threadIdx.x;   // over N_NODES*32 float4s
    if (t >= N_NODES * 32) return;
    float4 v = reinterpret_cast<const float4*>(x)[t];
    ushort4 h;
    h.x = f2h(v.x);
    h.y = f2h(v.y);
    h.z = f2h(v.z);
    h.w = f2h(v.w);
    reinterpret_cast<ushort4*>(H16)[t] = h;
}

// ---------------- mean aggregation: fp16 input rows (256B), 4 quarter-waves ----------------
__global__ __launch_bounds__(256) void aggregate_kernel(const unsigned short* __restrict__ hF16,
                                                        const int* __restrict__ offsets,
                                                        const int* __restrict__ csr_src,
                                                        const float* __restrict__ inv_deg,
                                                        unsigned short* __restrict__ aggH) {
    int node = blockIdx.x * 4 + (threadIdx.x >> 6);
    int lane = threadIdx.x & 63;
    int q = lane >> 4;       // 0..3
    int c = lane & 15;       // covers fp16 elems c*8..c*8+7
    if (node >= N_NODES) return;
    int beg = offsets[node];
    int end = offsets[node + 1];
    float a0[8], a1[8];
#pragma unroll
    for (int j = 0; j < 8; ++j) { a0[j] = 0.f; a1[j] = 0.f; }
    int e = beg + q;
    for (; e + 4 < end; e += 8) {
        int s0 = csr_src[e];
        int s1 = csr_src[e + 4];
        u16x8 v0 = *reinterpret_cast<const u16x8*>(hF16 + (size_t)s0 * 128 + c * 8);
        u16x8 v1 = *reinterpret_cast<const u16x8*>(hF16 + (size_t)s1 * 128 + c * 8);
#pragma unroll
        for (int j = 0; j < 8; ++j) {
            a0[j] += h2f(v0[j]);
            a1[j] += h2f(v1[j]);
        }
    }
    if (e < end) {
        int s0 = csr_src[e];
        u16x8 v0 = *reinterpret_cast<const u16x8*>(hF16 + (size_t)s0 * 128 + c * 8);
#pragma unroll
        for (int j = 0; j < 8; ++j) a0[j] += h2f(v0[j]);
    }
#pragma unroll
    for (int j = 0; j < 8; ++j) a0[j] += a1[j];
#pragma unroll
    for (int j = 0; j < 8; ++j) a0[j] += __shfl_xor(a0[j], 16, 64);
#pragma unroll
    for (int j = 0; j < 8; ++j) a0[j] += __shfl_xor(a0[j], 32, 64);
    if (q == 0) {
        float w = inv_deg[node];
        u16x8 hi;
#pragma unroll
        for (int j = 0; j < 8; ++j) hi[j] = f2bf_rn(a0[j] * w);
        *reinterpret_cast<u16x8*>(aggH + (size_t)node * 128 + c * 8) = hi;
    }
}

// ---------------- MFMA GEMM: triple-buffered counted-vmcnt pipeline ----------------
// Per buffer (16 KB): [Bh 8KB | Bl 8KB], chunk wv at wv*2048, row r at r*16 B.
// Per ks: A-load, stage(ks+1 -> (ks+1)%3), vmcnt(4) [retires A + cur stage, leaves
// next 4 in flight], raw s_barrier, MFMAs. Triple buffer => stage target was last
// read 2 iters ago, protected by barrier skew <= 1. No full vmcnt(0) drains.
template <int RELU, int LAST>
__global__ __launch_bounds__(256) void mfma_gemm_kernel(
    const unsigned short* __restrict__ aggH,
    const unsigned short* h16,
    const unsigned short* __restrict__ WH, const unsigned short* __restrict__ WL,
    const float* __restrict__ bias,
    float* __restrict__ OutF, unsigned short* H16o)
{
    __shared__ __align__(16) char smem[3 * 16384];
    const int tid = threadIdx.x;
    const int lane = tid & 63;
    const int wv = tid >> 6;           // 0..3
    const int m16 = lane & 15;
    const int kg = lane >> 4;          // 0..3
    const int blockRow = blockIdx.x * 64;
    const int rowg = blockRow + wv * 16 + m16;
    const int rowc = min(rowg, N_NODES - 1);

    f32x4 acc[8];
#pragma unroll
    for (int t = 0; t < 8; ++t) acc[t] = (f32x4){0.f, 0.f, 0.f, 0.f};

    // stage(ks, buf): wave wv stages its k-chunk (hi rows 0-63, 64-127; same for lo)
    auto stage = [&](int ks, int b) {
        const int kc = ks * 32;
        char* dst = smem + b * 16384 + wv * 2048;
        GLOAD16(WH + (size_t)lane * 256 + kc + wv * 8, dst);
        GLOAD16(WH + (size_t)(64 + lane) * 256 + kc + wv * 8, dst + 1024);
        GLOAD16(WL + (size_t)lane * 256 + kc + wv * 8, dst + 8192);
        GLOAD16(WL + (size_t)(64 + lane) * 256 + kc + wv * 8, dst + 8192 + 1024);
    };

    stage(0, 0);

    for (int ks = 0; ks < 8; ++ks) {
        const int kc = ks * 32;
        const int cur = ks % 3;
        bfrag a;
        if (ks < 4) {
            a = *reinterpret_cast<const bfrag*>(aggH + (size_t)rowc * 128 + kc + kg * 8);
        } else {
            u16x8 hv = *reinterpret_cast<const u16x8*>(h16 + (size_t)rowc * 128 + (kc - 128) + kg * 8);
#pragma unroll
            for (int j = 0; j < 8; ++j) a[j] = (short)f2bf_rn(h2f(hv[j]));
        }
        if (ks < 7) {
            stage(ks + 1, (ks + 1) % 3);
            asm volatile("s_waitcnt vmcnt(4)" ::: "memory");
        } else {
            asm volatile("s_waitcnt vmcnt(0)" ::: "memory");
        }
        __builtin_amdgcn_s_barrier();
        __builtin_amdgcn_sched_barrier(0);
        const unsigned short* Bh = (const unsigned short*)(smem + cur * 16384 + kg * 2048);
        const unsigned short* Bl = (const unsigned short*)(smem + cur * 16384 + 8192 + kg * 2048);
#pragma unroll
        for (int t = 0; t < 8; ++t) {
            bfrag bh = *reinterpret_cast<const bfrag*>(Bh + (t * 16 + m16) * 8);
            bfrag bl = *reinterpret_cast<const bfrag*>(Bl + (t * 16 + m16) * 8);
            acc[t] = __builtin_amdgcn_mfma_f32_16x16x32_bf16(a, bh, acc[t], 0, 0, 0);
            acc[t] = __builtin_amdgcn_mfma_f32_16x16x32_bf16(a, bl, acc[t], 0, 0, 0);
        }
    }

#pragma unroll
    for (int t = 0; t < 8; ++t) {
        int col = t * 16 + m16;
        float bv = bias[col];
#pragma unroll
        for (int r = 0; r < 4; ++r) {
            int row = blockRow + wv * 16 + kg * 4 + r;
            if (row >= N_NODES) continue;
            float v = acc[t][r] + bv;
            if (RELU) v = fmaxf(v, 0.f);
            if (LAST) {
                OutF[(size_t)row * 128 + col] = v;
            } else {
                H16o[(size_t)row * 128 + col] = f2h(v);
            }
        }
    }
}

extern "C" void kernel_launch(void* const* d_in, const int* in_sizes, int n_in,
                              void* d_out, int out_size, void* d_ws, size_t ws_size,
                              hipStream_t stream) {
    const float* x  = (const float*)d_in[0];
    const int*   ei = (const int*)d_in[1];
    const float* Wl = (const float*)d_in[2];
    const float* bl = (const float*)d_in[3];
    const float* Wr = (const float*)d_in[4];
    float* out = (float*)d_out;
    char* ws = (char*)d_ws;

    int*            flag     = (int*)(ws + 0);
    int*            gcoarse  = (int*)(ws + 1024);
    int*            cursor1  = (int*)(ws + 3072);
    int*            offs     = (int*)(ws + 4096);
    float*          invd     = (float*)(ws + 208896);
    int*            packed   = (int*)(ws + 409600);
    int*            csr      = (int*)(ws + 3609600);
    unsigned short* WH       = (unsigned short*)(ws + 6809600);
    unsigned short* WL       = (unsigned short*)(ws + 7006208);
    unsigned short* h16      = (unsigned short*)(ws + 7202816);
    unsigned short* aggH     = (unsigned short*)(ws + 20002816);
    // total ws use ~32.8 MB

    detect_dtype_kernel<<<1, 256, 0, stream>>>((const unsigned int*)ei, flag, gcoarse, cursor1);
    hist_coarse_kernel<<<(N_EDGES + 1023) / 1024, 256, 0, stream>>>(ei, flag, gcoarse);
    pass1_kernel<<<(N_EDGES + 4095) / 4096, 256, 0, stream>>>(ei, flag, gcoarse, cursor1, packed);
    build_csr_kernel<<<NBUCK, 256, 0, stream>>>(gcoarse, packed, offs, invd, csr);
    prep_w_kernel<<<(N_LAYERS * 128 * 256 + 255) / 256, 256, 0, stream>>>(Wl, Wr, WH, WL);
    split_x_kernel<<<(N_NODES * 32 + 255) / 256, 256, 0, stream>>>(x, h16);

    const int aggGrid = N_NODES / 4;            // 12500
    const int gemmGrid = (N_NODES + 63) / 64;   // 782

    // layer 0
    aggregate_kernel<<<aggGrid, 256, 0, stream>>>(h16, offs, csr, invd, aggH);
    mfma_gemm_kernel<1, 0><<<gemmGrid, 256, 0, stream>>>(aggH, h16,
        WH + 0 * 32768, WL + 0 * 32768, bl + 0, nullptr, h16);
    // layer 1
    aggregate_kernel<<<aggGrid, 256, 0, stream>>>(h16, offs, csr, invd, aggH);
    mfma_gemm_kernel<1, 0><<<gemmGrid, 256, 0, stream>>>(aggH, h16,
        WH + 1 * 32768, WL + 1 * 32768, bl + 128, nullptr, h16);
    // layer 2: final fp32 into d_out
    aggregate_kernel<<<aggGrid, 256, 0, stream>>>(h16, offs, csr, invd, aggH);
    mfma_gemm_kernel<0, 1><<<gemmGrid, 256, 0, stream>>>(aggH, h16,
        WH + 2 * 32768, WL + 2 * 32768, bl + 256, out, nullptr);
}

// Round 14
// 209.761 us; speedup vs baseline: 1.1997x; 1.1997x over previous
//
#include <hip/hip_runtime.h>

#define N_NODES 50000
#define N_EDGES 800000
#define D 128
#define N_LAYERS 3
#define NBUCK ((N_NODES + 255) / 256)       // 196 coarse buckets (256 nodes each)

typedef __attribute__((ext_vector_type(8))) short bfrag;
typedef __attribute__((ext_vector_type(4))) float f32x4;
typedef __attribute__((ext_vector_type(8))) unsigned short u16x8;

__device__ __forceinline__ unsigned short f2bf_rn(float f) {
    union { float f; unsigned u; } a; a.f = f;
    unsigned r = a.u + 0x7fffu + ((a.u >> 16) & 1u);
    return (unsigned short)(r >> 16);
}
__device__ __forceinline__ unsigned short f2h(float f) {
    union { unsigned short s[1]; _Float16 h; } a; a.h = (_Float16)f; return a.s[0];
}
__device__ __forceinline__ float h2f(unsigned short u) {
    union { unsigned short s[1]; _Float16 h; } a; a.s[0] = u; return (float)a.h;
}

#define GLOAD16(g, l) __builtin_amdgcn_global_load_lds( \
    (const __attribute__((address_space(1))) void*)(g), \
    (__attribute__((address_space(3))) void*)(l), 16, 0, 0)

// ---------------- detect dtype + zero coarse histogram & cursors ----------------
__global__ void detect_dtype_kernel(const unsigned int* __restrict__ edge, int* __restrict__ flag,
                                    int* __restrict__ gcoarse, int* __restrict__ cursor1) {
    __shared__ int any_nz;
    if (threadIdx.x == 0) any_nz = 0;
    __syncthreads();
    int nz = 0;
    for (int i = threadIdx.x; i < 2048; i += blockDim.x) {
        if (edge[2 * i + 1] != 0u) nz = 1;
    }
    if (nz) atomicOr(&any_nz, 1);
    for (int i = threadIdx.x; i < NBUCK; i += blockDim.x) { gcoarse[i] = 0; cursor1[i] = 0; }
    __syncthreads();
    if (threadIdx.x == 0) *flag = any_nz ? 0 : 1;   // 1 => int64 layout
}

// ---------------- coarse histogram (196 bins) straight off edge buffer ----------------
__global__ __launch_bounds__(256) void hist_coarse_kernel(const int* __restrict__ edge,
                                                          const int* __restrict__ flag,
                                                          int* __restrict__ gcoarse) {
    __shared__ int h[NBUCK];
    const int t = threadIdx.x;
    for (int i = t; i < NBUCK; i += 256) h[i] = 0;
    __syncthreads();
    const int flagv = *flag;
    const int base = blockIdx.x * 1024;
#pragma unroll
    for (int j = 0; j < 4; ++j) {
        int i = base + j * 256 + t;
        if (i < N_EDGES) {
            int d = flagv ? edge[2 * ((size_t)N_EDGES + i)] : edge[N_EDGES + i];
            atomicAdd(&h[d >> 8], 1);
        }
    }
    __syncthreads();
    for (int i = t; i < NBUCK; i += 256)
        if (h[i]) atomicAdd(&gcoarse[i], h[i]);
}

// ---------------- pass 1: coarse bucket scatter; bucket bases computed locally -------
__global__ __launch_bounds__(256) void pass1_kernel(const int* __restrict__ edge,
                                                    const int* __restrict__ flag,
                                                    const int* __restrict__ gcoarse,
                                                    int* __restrict__ cursor1,
                                                    int* __restrict__ packed) {
    __shared__ int hist[NBUCK];
    __shared__ int lbase[256];
    __shared__ int base[NBUCK];
    const int t = threadIdx.x;
    const int flagv = *flag;
    const int blockBeg = blockIdx.x * 4096;
    for (int i = t; i < NBUCK; i += 256) hist[i] = 0;
    // local exclusive scan of gcoarse -> lbase
    {
        int v = (t < NBUCK) ? gcoarse[t] : 0;
        lbase[t] = v;
        __syncthreads();
        for (int off = 1; off < 256; off <<= 1) {
            int u = (t >= off) ? lbase[t - off] : 0;
            __syncthreads();
            lbase[t] += u;
            __syncthreads();
        }
        lbase[t] -= v;   // exclusive
    }
    int es[16], ed[16];
#pragma unroll
    for (int j = 0; j < 16; ++j) {
        int e = blockBeg + j * 256 + t;   // coalesced
        if (e < N_EDGES) {
            if (flagv) { es[j] = edge[2 * (size_t)e]; ed[j] = edge[2 * ((size_t)N_EDGES + e)]; }
            else       { es[j] = edge[e];             ed[j] = edge[N_EDGES + e]; }
        } else ed[j] = -1;
    }
#pragma unroll
    for (int j = 0; j < 16; ++j)
        if (ed[j] >= 0) atomicAdd(&hist[ed[j] >> 8], 1);
    __syncthreads();
    for (int i = t; i < NBUCK; i += 256) {
        base[i] = lbase[i] + atomicAdd(&cursor1[i], hist[i]);
        hist[i] = 0;                       // reuse as within-block cursor
    }
    __syncthreads();
#pragma unroll
    for (int j = 0; j < 16; ++j) {
        if (ed[j] >= 0) {
            int b = ed[j] >> 8;
            int pos = base[b] + atomicAdd(&hist[b], 1);
            packed[pos] = ((ed[j] & 255) << 18) | es[j];
        }
    }
}

// ---------------- build CSR: local bucket bases + per-bucket count/scan/scatter ------
__global__ __launch_bounds__(256) void build_csr_kernel(const int* __restrict__ gcoarse,
                                                        const int* __restrict__ packed,
                                                        int* __restrict__ offsets,
                                                        float* __restrict__ inv_deg,
                                                        int* __restrict__ csr) {
    __shared__ int cnt[256];
    __shared__ int s[256];
    __shared__ int lbase[256];
    const int t = threadIdx.x;
    const int b = blockIdx.x;
    {
        int v = (t < NBUCK) ? gcoarse[t] : 0;
        lbase[t] = v;
        __syncthreads();
        for (int off = 1; off < 256; off <<= 1) {
            int u = (t >= off) ? lbase[t - off] : 0;
            __syncthreads();
            lbase[t] += u;
            __syncthreads();
        }
    }
    const int base = (b == 0) ? 0 : lbase[b - 1];
    const int endb = lbase[b];
    cnt[t] = 0;
    __syncthreads();
    for (int e = base + t; e < endb; e += 256)
        atomicAdd(&cnt[((unsigned)packed[e]) >> 18], 1);
    __syncthreads();
    int v = cnt[t];
    s[t] = v;
    __syncthreads();
    for (int off = 1; off < 256; off <<= 1) {
        int u = (t >= off) ? s[t - off] : 0;
        __syncthreads();
        s[t] += u;
        __syncthreads();
    }
    int excl = base + s[t] - v;
    int node = b * 256 + t;
    if (node < N_NODES) {
        offsets[node] = excl;
        inv_deg[node] = 1.0f / (float)max(v, 1);
    }
    if (b == NBUCK - 1 && t == 0) offsets[N_NODES] = N_EDGES;
    cnt[t] = excl;                        // reuse as per-node cursor
    __syncthreads();
    for (int e = base + t; e < endb; e += 256) {
        int p = packed[e];
        int pos = atomicAdd(&cnt[((unsigned)p) >> 18], 1);
        csr[pos] = p & 0x3FFFF;
    }
}

// ---------------- weight prep: Wt[l][j][k] (k contiguous), single bf16 ----------------
__global__ void prep_w_kernel(const float* __restrict__ Wl, const float* __restrict__ Wr,
                              unsigned short* __restrict__ WH) {
    int idx = blockIdx.x * blockDim.x + threadIdx.x;
    if (idx >= N_LAYERS * 128 * 256) return;
    int k = idx & 255;
    int j = (idx >> 8) & 127;
    int l = idx >> 15;
    float v = (k < 128) ? Wl[((size_t)l * 128 + j) * 128 + k]
                        : Wr[((size_t)l * 128 + j) * 128 + (k - 128)];
    WH[idx] = f2bf_rn(v);
}

// ---------------- x -> fp16 ----------------
__global__ void split_x_kernel(const float* __restrict__ x, unsigned short* __restrict__ H16) {
    int t = blockIdx.x * 256 + threadIdx.x;   // over N_NODES*32 float4s
    if (t >= N_NODES * 32) return;
    float4 v = reinterpret_cast<const float4*>(x)[t];
    ushort4 h;
    h.x = f2h(v.x);
    h.y = f2h(v.y);
    h.z = f2h(v.z);
    h.w = f2h(v.w);
    reinterpret_cast<ushort4*>(H16)[t] = h;
}

// ---------------- mean aggregation: fp16 input rows (256B), 4 quarter-waves ----------------
__global__ __launch_bounds__(256) void aggregate_kernel(const unsigned short* __restrict__ hF16,
                                                        const int* __restrict__ offsets,
                                                        const int* __restrict__ csr_src,
                                                        const float* __restrict__ inv_deg,
                                                        unsigned short* __restrict__ aggH) {
    int node = blockIdx.x * 4 + (threadIdx.x >> 6);
    int lane = threadIdx.x & 63;
    int q = lane >> 4;       // 0..3
    int c = lane & 15;       // covers fp16 elems c*8..c*8+7
    if (node >= N_NODES) return;
    int beg = offsets[node];
    int end = offsets[node + 1];
    float a0[8], a1[8];
#pragma unroll
    for (int j = 0; j < 8; ++j) { a0[j] = 0.f; a1[j] = 0.f; }
    int e = beg + q;
    for (; e + 4 < end; e += 8) {
        int s0 = csr_src[e];
        int s1 = csr_src[e + 4];
        u16x8 v0 = *reinterpret_cast<const u16x8*>(hF16 + (size_t)s0 * 128 + c * 8);
        u16x8 v1 = *reinterpret_cast<const u16x8*>(hF16 + (size_t)s1 * 128 + c * 8);
#pragma unroll
        for (int j = 0; j < 8; ++j) {
            a0[j] += h2f(v0[j]);
            a1[j] += h2f(v1[j]);
        }
    }
    if (e < end) {
        int s0 = csr_src[e];
        u16x8 v0 = *reinterpret_cast<const u16x8*>(hF16 + (size_t)s0 * 128 + c * 8);
#pragma unroll
        for (int j = 0; j < 8; ++j) a0[j] += h2f(v0[j]);
    }
#pragma unroll
    for (int j = 0; j < 8; ++j) a0[j] += a1[j];
#pragma unroll
    for (int j = 0; j < 8; ++j) a0[j] += __shfl_xor(a0[j], 16, 64);
#pragma unroll
    for (int j = 0; j < 8; ++j) a0[j] += __shfl_xor(a0[j], 32, 64);
    if (q == 0) {
        float w = inv_deg[node];
        u16x8 hi;
#pragma unroll
        for (int j = 0; j < 8; ++j) hi[j] = f2bf_rn(a0[j] * w);
        *reinterpret_cast<u16x8*>(aggH + (size_t)node * 128 + c * 8) = hi;
    }
}

// ---------------- MFMA GEMM: C = [agg|h] @ W^T + bias, single-bf16 W ----------------
// R12's proven 2-barrier LDS-staged structure, halved: 2 gload/ks, 8 MFMAs/ks, 8 KB LDS.
// A: ks<4 from aggH (bf16 direct), ks>=4 from h16 (fp16 -> bf16 in-register).
// Non-LAST epilogue writes h16 in-place (safe: block reads only its own rows).
template <int RELU, int LAST>
__global__ __launch_bounds__(256) void mfma_gemm_kernel(
    const unsigned short* __restrict__ aggH,
    const unsigned short* h16,
    const unsigned short* __restrict__ WH,
    const float* __restrict__ bias,
    float* __restrict__ OutF, unsigned short* H16o)
{
    __shared__ __align__(16) unsigned short Bh[4][128][8];
    const int tid = threadIdx.x;
    const int lane = tid & 63;
    const int wv = tid >> 6;           // 0..3
    const int m16 = lane & 15;
    const int kg = lane >> 4;          // 0..3
    const int blockRow = blockIdx.x * 64;
    const int rowg = blockRow + wv * 16 + m16;
    const int rowc = min(rowg, N_NODES - 1);

    f32x4 acc[8];
#pragma unroll
    for (int t = 0; t < 8; ++t) acc[t] = (f32x4){0.f, 0.f, 0.f, 0.f};

    for (int ks = 0; ks < 8; ++ks) {
        const int kc = ks * 32;
        bfrag a;
        if (ks < 4) {
            a = *reinterpret_cast<const bfrag*>(aggH + (size_t)rowc * 128 + kc + kg * 8);
        } else {
            u16x8 hv = *reinterpret_cast<const u16x8*>(h16 + (size_t)rowc * 128 + (kc - 128) + kg * 8);
#pragma unroll
            for (int j = 0; j < 8; ++j) a[j] = (short)f2bf_rn(h2f(hv[j]));
        }
        {
            GLOAD16(WH + (size_t)lane * 256 + kc + wv * 8,
                    (char*)&Bh[0][0][0] + wv * 2048);
            GLOAD16(WH + (size_t)(64 + lane) * 256 + kc + wv * 8,
                    (char*)&Bh[0][0][0] + wv * 2048 + 1024);
        }
        __syncthreads();
#pragma unroll
        for (int t = 0; t < 8; ++t) {
            bfrag bh = *reinterpret_cast<const bfrag*>(&Bh[kg][t * 16 + m16][0]);
            acc[t] = __builtin_amdgcn_mfma_f32_16x16x32_bf16(a, bh, acc[t], 0, 0, 0);
        }
        __syncthreads();
    }

#pragma unroll
    for (int t = 0; t < 8; ++t) {
        int col = t * 16 + m16;
        float bv = bias[col];
#pragma unroll
        for (int r = 0; r < 4; ++r) {
            int row = blockRow + wv * 16 + kg * 4 + r;
            if (row >= N_NODES) continue;
            float v = acc[t][r] + bv;
            if (RELU) v = fmaxf(v, 0.f);
            if (LAST) {
                OutF[(size_t)row * 128 + col] = v;
            } else {
                H16o[(size_t)row * 128 + col] = f2h(v);
            }
        }
    }
}

extern "C" void kernel_launch(void* const* d_in, const int* in_sizes, int n_in,
                              void* d_out, int out_size, void* d_ws, size_t ws_size,
                              hipStream_t stream) {
    const float* x  = (const float*)d_in[0];
    const int*   ei = (const int*)d_in[1];
    const float* Wl = (const float*)d_in[2];
    const float* bl = (const float*)d_in[3];
    const float* Wr = (const float*)d_in[4];
    float* out = (float*)d_out;
    char* ws = (char*)d_ws;

    int*            flag     = (int*)(ws + 0);
    int*            gcoarse  = (int*)(ws + 1024);
    int*            cursor1  = (int*)(ws + 3072);
    int*            offs     = (int*)(ws + 4096);
    float*          invd     = (float*)(ws + 208896);
    int*            packed   = (int*)(ws + 409600);
    int*            csr      = (int*)(ws + 3609600);
    unsigned short* WH       = (unsigned short*)(ws + 6809600);
    unsigned short* h16      = (unsigned short*)(ws + 7202816);
    unsigned short* aggH     = (unsigned short*)(ws + 20002816);
    // total ws use ~32.8 MB

    detect_dtype_kernel<<<1, 256, 0, stream>>>((const unsigned int*)ei, flag, gcoarse, cursor1);
    hist_coarse_kernel<<<(N_EDGES + 1023) / 1024, 256, 0, stream>>>(ei, flag, gcoarse);
    pass1_kernel<<<(N_EDGES + 4095) / 4096, 256, 0, stream>>>(ei, flag, gcoarse, cursor1, packed);
    build_csr_kernel<<<NBUCK, 256, 0, stream>>>(gcoarse, packed, offs, invd, csr);
    prep_w_kernel<<<(N_LAYERS * 128 * 256 + 255) / 256, 256, 0, stream>>>(Wl, Wr, WH);
    split_x_kernel<<<(N_NODES * 32 + 255) / 256, 256, 0, stream>>>(x, h16);

    const int aggGrid = N_NODES / 4;            // 12500
    const int gemmGrid = (N_NODES + 63) / 64;   // 782

    // layer 0
    aggregate_kernel<<<aggGrid, 256, 0, stream>>>(h16, offs, csr, invd, aggH);
    mfma_gemm_kernel<1, 0><<<gemmGrid, 256, 0, stream>>>(aggH, h16,
        WH + 0 * 32768, bl + 0, nullptr, h16);
    // layer 1
    aggregate_kernel<<<aggGrid, 256, 0, stream>>>(h16, offs, csr, invd, aggH);
    mfma_gemm_kernel<1, 0><<<gemmGrid, 256, 0, stream>>>(aggH, h16,
        WH + 1 * 32768, bl + 128, nullptr, h16);
    // layer 2: final fp32 into d_out
    aggregate_kernel<<<aggGrid, 256, 0, stream>>>(h16, offs, csr, invd, aggH);
    mfma_gemm_kernel<0, 1><<<gemmGrid, 256, 0, stream>>>(aggH, h16,
        WH + 2 * 32768, bl + 256, out, nullptr);
}